// Round 4
// baseline (288.162 us; speedup 1.0000x reference)
//
#include <hip/hip_runtime.h>
#include <cstdint>
#include <cstddef>

#define PASSA_EDGES 8192
#define PASSB_CAP   12288   // LDS csr-image capacity (ints); padded max bucket ~10.5k for this input

// ---------------- bf16 helpers ----------------

__device__ __forceinline__ unsigned short f2bf(float f) {  // RNE
    unsigned int u = __float_as_uint(f);
    u += 0x7FFFu + ((u >> 16) & 1u);
    return (unsigned short)(u >> 16);
}

// fma 8 bf16 (packed in uint4) * w into acc[8]
__device__ __forceinline__ void bf8_fma(uint4 u, float w, float* acc) {
    acc[0] += __uint_as_float(u.x << 16) * w;
    acc[1] += __uint_as_float(u.x & 0xFFFF0000u) * w;
    acc[2] += __uint_as_float(u.y << 16) * w;
    acc[3] += __uint_as_float(u.y & 0xFFFF0000u) * w;
    acc[4] += __uint_as_float(u.z << 16) * w;
    acc[5] += __uint_as_float(u.z & 0xFFFF0000u) * w;
    acc[6] += __uint_as_float(u.w << 16) * w;
    acc[7] += __uint_as_float(u.w & 0xFFFF0000u) * w;
}
__device__ __forceinline__ void bf8_unpack(uint4 u, float* v) {
    v[0] = __uint_as_float(u.x << 16);
    v[1] = __uint_as_float(u.x & 0xFFFF0000u);
    v[2] = __uint_as_float(u.y << 16);
    v[3] = __uint_as_float(u.y & 0xFFFF0000u);
    v[4] = __uint_as_float(u.z << 16);
    v[5] = __uint_as_float(u.z & 0xFFFF0000u);
    v[6] = __uint_as_float(u.w << 16);
    v[7] = __uint_as_float(u.w & 0xFFFF0000u);
}

// ---------------- bucket cursor init ----------------

__global__ void bcur_init(int* __restrict__ bcur, int NBUCK, int CAP) {
    int b = threadIdx.x;
    if (b < NBUCK) bcur[b] = b * CAP;
}

// ---------------- pass A: bin (src,dst) by coarse dst bucket into slabs ----------------

__global__ __launch_bounds__(256) void passA(const int* __restrict__ src,
                                             const int* __restrict__ dst,
                                             int* __restrict__ bcur,
                                             int2* __restrict__ bbuf, int E,
                                             int CAP, int shift) {
    __shared__ int2 bins[PASSA_EDGES];
    __shared__ int  cnt[256], off[256], cur[256], gbase[256];
    const int t  = threadIdx.x;
    const int e0 = blockIdx.x * PASSA_EDGES;
    const int n  = min(PASSA_EDGES, E - e0);

    cnt[t] = 0;
    __syncthreads();
    for (int i = t; i < n; i += 256) atomicAdd(&cnt[dst[e0 + i] >> shift], 1);
    __syncthreads();

    int v = cnt[t];
    off[t] = v;
    __syncthreads();
    for (int o = 1; o < 256; o <<= 1) {
        int u = (t >= o) ? off[t - o] : 0;
        __syncthreads();
        off[t] += u;
        __syncthreads();
    }
    int excl = off[t] - v;
    off[t]   = excl;
    cur[t]   = excl;
    __syncthreads();

    for (int i = t; i < n; i += 256) {
        int d = dst[e0 + i];
        int s = src[e0 + i];
        int p = atomicAdd(&cur[d >> shift], 1);
        bins[p] = make_int2(s, d);
    }
    if (cnt[t] > 0) gbase[t] = atomicAdd(&bcur[t], cnt[t]);
    __syncthreads();

    const int w = t >> 6, lane = t & 63;
    for (int b = w; b < 256; b += 4) {
        int c = cnt[b];
        if (c == 0) continue;
        int lo  = off[b], go = gbase[b];
        int lim = (b + 1) * CAP;
        if (go + c > lim) c = max(0, lim - go);
        for (int i = lane; i < c; i += 64) bbuf[go + i] = bins[lo + i];
    }
}

// ---------------- per-bucket histogram + dis ----------------
// hist holds the 8-PADDED degree (slab quantum for the shuffle-free gather);
// dis uses the true degree.

__global__ __launch_bounds__(256) void hist_dis(const int2* __restrict__ bbuf,
                                                const int* __restrict__ bcur,
                                                int* __restrict__ hist,
                                                float* __restrict__ dis,
                                                int N, int CAP, int shift) {
    __shared__ int cnt[1024];
    const int b     = blockIdx.x;
    const int node0 = b << shift;
    const int nn    = min(1 << shift, N - node0);
    for (int j = threadIdx.x; j < nn; j += 256) cnt[j] = 0;
    __syncthreads();
    const int start = b * CAP, end = bcur[b];
    for (int e = start + threadIdx.x; e < end; e += 256)
        atomicAdd(&cnt[bbuf[e].y - node0], 1);
    __syncthreads();
    for (int j = threadIdx.x; j < nn; j += 256) {
        int c = cnt[j];
        hist[node0 + j] = (c + 7) & ~7;            // padded slab size
        dis[node0 + j]  = rsqrtf((float)(c + 1));  // +1 self loop (true degree)
    }
}

// ---------------- 3-phase exclusive scan hist[0..N) -> ptr[0..N] ----------------

__global__ __launch_bounds__(256) void scan_partial(const int* __restrict__ hist,
                                                    int* __restrict__ partials, int N) {
    __shared__ int red[256];
    const int t    = threadIdx.x;
    const int base = blockIdx.x * 1024 + t * 4;
    int s = 0;
    if (base + 3 < N) {
        int4 v = *(const int4*)&hist[base];
        s = v.x + v.y + v.z + v.w;
    } else {
        for (int i = 0; i < 4; i++)
            if (base + i < N) s += hist[base + i];
    }
    red[t] = s;
    __syncthreads();
    for (int off = 128; off; off >>= 1) {
        if (t < off) red[t] += red[t + off];
        __syncthreads();
    }
    if (t == 0) partials[blockIdx.x] = red[0];
}

__global__ __launch_bounds__(256) void scan_offsets(int* __restrict__ partials, int NB) {
    __shared__ int tmp[256];
    const int t = threadIdx.x;
    int v = (t < NB) ? partials[t] : 0;
    tmp[t] = v;
    __syncthreads();
    for (int off = 1; off < 256; off <<= 1) {
        int u = (t >= off) ? tmp[t - off] : 0;
        __syncthreads();
        tmp[t] += u;
        __syncthreads();
    }
    if (t < NB) partials[t] = tmp[t] - v;
}

__global__ __launch_bounds__(256) void scan_apply(const int* __restrict__ hist,
                                                  const int* __restrict__ partials,
                                                  int* __restrict__ ptr, int N) {
    __shared__ int tsum[256];
    const int t    = threadIdx.x;
    const int base = blockIdx.x * 1024 + t * 4;
    int v[4];
    int s = 0;
    for (int i = 0; i < 4; i++) {
        v[i] = (base + i < N) ? hist[base + i] : 0;
        s += v[i];
    }
    tsum[t] = s;
    __syncthreads();
    for (int off = 1; off < 256; off <<= 1) {
        int u = (t >= off) ? tsum[t - off] : 0;
        __syncthreads();
        tsum[t] += u;
        __syncthreads();
    }
    int run = partials[blockIdx.x] + tsum[t] - s;
    for (int i = 0; i < 4; i++) {
        if (base + i < N) {
            ptr[base + i] = run;
            run += v[i];
        }
    }
    if (base <= N - 1 && N - 1 < base + 4) ptr[N] = run;  // total = padded E
}

// ---------------- pass B: per-bucket LDS scatter -> padded (src,w) csr write -------
// csrw[e] = {src, bitcast(dis[src])}; pad slots (up to 7 per row) = {0, 0.0f}:
// they load row 0 (L1-hot) and fma by 0 in the gather -- branch-free slop.

__global__ __launch_bounds__(256) void passB(const int2* __restrict__ bbuf,
                                             const int* __restrict__ bcur,
                                             const int* __restrict__ ptr,
                                             int2* __restrict__ csrw,
                                             const float* __restrict__ dis,
                                             int N, int CAP, int shift) {
    __shared__ int lcnt[1024];
    __shared__ int lcsr[PASSB_CAP];
    const int b     = blockIdx.x;
    const int node0 = b << shift;
    const int nn    = min(1 << shift, N - node0);
    const int cbase = ptr[node0];
    const int csize = ptr[node0 + nn] - cbase;   // padded size

    for (int j = threadIdx.x; j < nn; j += 256) lcnt[j] = ptr[node0 + j] - cbase;
    __syncthreads();

    const int start = b * CAP, end = bcur[b];
    if (csize <= PASSB_CAP) {
        for (int i = threadIdx.x; i < csize; i += 256) lcsr[i] = -1;  // pad marker
        __syncthreads();
        for (int e = start + threadIdx.x; e < end; e += 256) {
            int2 pr = bbuf[e];
            int  p  = atomicAdd(&lcnt[pr.y - node0], 1);
            lcsr[p] = pr.x;
        }
        __syncthreads();
        for (int i = threadIdx.x; i < csize; i += 256) {
            int s = lcsr[i];
            csrw[cbase + i] = (s < 0) ? make_int2(0, 0)
                                      : make_int2(s, __float_as_int(dis[s]));
        }
    } else {  // fallback: default-fill then direct global scatter
        for (int i = threadIdx.x; i < csize; i += 256) csrw[cbase + i] = make_int2(0, 0);
        __syncthreads();
        for (int e = start + threadIdx.x; e < end; e += 256) {
            int2 pr = bbuf[e];
            int  p  = atomicAdd(&lcnt[pr.y - node0], 1);
            csrw[cbase + p] = make_int2(pr.x, __float_as_int(dis[pr.x]));
        }
    }
}

// ---------------- GEMM: Yb[N x 64](bf16) = X[N x K](f32) @ W[K x 64] ---------------
// R4: W-only LDS (32/16 KB). X comes straight from global: the 4 row-quads of a
// wave are shared by its 16 cg-lanes -> each load instr touches 4 unique 16B
// segments (hw broadcast), L1-served, X streamed once. OOB rows clamp their
// pointer to row N-1 (in-bounds load, discarded by the store predicate).
// Old xs+ws layout was 66.5KB LDS -> 2 blocks/CU (16% occ) AND LDS-BW-bound
// (1MB/block LDS reads = 4096 cyc = FMA cyc). W-only: 5+ blocks/CU, LDS halved.
// #pragma unroll 2 REQUIRED (full unroll -> 256 VGPR + scratch spill, R6).

template <int K>
__global__ __launch_bounds__(256) void gemm64_bf16(const float* __restrict__ X,
                                                   const float* __restrict__ W,
                                                   unsigned short* __restrict__ Yb, int N) {
    __shared__ float ws[K * 64];
    const int tid  = threadIdx.x;
    const int row0 = blockIdx.x * 64;

    const float4* W4 = (const float4*)W;
    for (int i = tid; i < K * 16; i += 256) ((float4*)ws)[i] = W4[i];

    const int cg = tid & 15;
    const int rg = tid >> 4;

    const float* xr[4];
#pragma unroll
    for (int i = 0; i < 4; i++) {
        int r = row0 + rg * 4 + i;
        xr[i] = X + (size_t)min(r, N - 1) * K;   // clamped: always in-bounds
    }
    __syncthreads();

    float acc[4][4] = {};
#pragma unroll 2
    for (int k = 0; k < K; k += 4) {
        float4 xf[4], wf[4];
#pragma unroll
        for (int i = 0; i < 4; i++) xf[i] = *(const float4*)(xr[i] + k);
#pragma unroll
        for (int j = 0; j < 4; j++) wf[j] = *(const float4*)&ws[(k + j) * 64 + cg * 4];
#pragma unroll
        for (int i = 0; i < 4; i++) {
            float4 xv = xf[i];
            acc[i][0] += xv.x * wf[0].x + xv.y * wf[1].x + xv.z * wf[2].x + xv.w * wf[3].x;
            acc[i][1] += xv.x * wf[0].y + xv.y * wf[1].y + xv.z * wf[2].y + xv.w * wf[3].y;
            acc[i][2] += xv.x * wf[0].z + xv.y * wf[1].z + xv.z * wf[2].z + xv.w * wf[3].z;
            acc[i][3] += xv.x * wf[0].w + xv.y * wf[1].w + xv.z * wf[2].w + xv.w * wf[3].w;
        }
    }

#pragma unroll
    for (int i = 0; i < 4; i++) {
        int r = row0 + rg * 4 + i;
        if (r < N) {
            ushort4 o;
            o.x = f2bf(acc[i][0]); o.y = f2bf(acc[i][1]);
            o.z = f2bf(acc[i][2]); o.w = f2bf(acc[i][3]);
            *(ushort4*)&Yb[(size_t)r * 64 + cg * 4] = o;
        }
    }
}

// ---------------- shuffle-free oct-row gather: 8 rows/wave, group-per-row ----------
// Row slabs are 8-padded (s0 % 8 == 0), so each lane loads its group's whole
// (src,w) chunk directly as 4 x int4 (64B, all 8 group lanes hit the same L1
// lines -> broadcast). No ds_bpermute, no bounds predication in the loop.
// Next chunk is prefetched one iteration ahead; 8 independent B-row loads are
// in flight per lane per iteration. Groups exit independently (divergence safe).

__device__ __forceinline__ void gather8_pad(const unsigned short* __restrict__ B,
                                            const int2* __restrict__ csrw,
                                            int s0, int iters, int co, float* acc) {
    const int4* cs = (const int4*)(csrw + s0);  // 64B-aligned (s0 % 8 == 0)
    int4 c0 = make_int4(0, 0, 0, 0), c1 = c0, c2 = c0, c3 = c0;
    if (iters > 0) { c0 = cs[0]; c1 = cs[1]; c2 = cs[2]; c3 = cs[3]; }
    for (int it = 0; it < iters; ++it) {
        const int nb = min(it + 1, iters - 1) * 4;   // prefetch next chunk (clamped)
        int4 n0 = cs[nb], n1 = cs[nb + 1], n2 = cs[nb + 2], n3 = cs[nb + 3];
        uint4 u0 = *(const uint4*)&B[(size_t)c0.x * 64 + co * 8];
        uint4 u1 = *(const uint4*)&B[(size_t)c0.z * 64 + co * 8];
        uint4 u2 = *(const uint4*)&B[(size_t)c1.x * 64 + co * 8];
        uint4 u3 = *(const uint4*)&B[(size_t)c1.z * 64 + co * 8];
        uint4 u4 = *(const uint4*)&B[(size_t)c2.x * 64 + co * 8];
        uint4 u5 = *(const uint4*)&B[(size_t)c2.z * 64 + co * 8];
        uint4 u6 = *(const uint4*)&B[(size_t)c3.x * 64 + co * 8];
        uint4 u7 = *(const uint4*)&B[(size_t)c3.z * 64 + co * 8];
        bf8_fma(u0, __int_as_float(c0.y), acc);
        bf8_fma(u1, __int_as_float(c0.w), acc);
        bf8_fma(u2, __int_as_float(c1.y), acc);
        bf8_fma(u3, __int_as_float(c1.w), acc);
        bf8_fma(u4, __int_as_float(c2.y), acc);
        bf8_fma(u5, __int_as_float(c2.w), acc);
        bf8_fma(u6, __int_as_float(c3.y), acc);
        bf8_fma(u7, __int_as_float(c3.w), acc);
        c0 = n0; c1 = n1; c2 = n2; c3 = n3;
    }
}

// ---------------- layer 1: pure gather + relu -> f32 h (scratch = d_out) -----------
// De-fused: no W2 tail, no LDS. gemm2 runs as a standalone tiled kernel after.

__global__ __launch_bounds__(256) void agg_l1(const unsigned short* __restrict__ B,
                                              const int2* __restrict__ csrw,
                                              const int* __restrict__ ptr,
                                              const float* __restrict__ dis,
                                              const float* __restrict__ b1,
                                              float* __restrict__ hs, int N) {
    const int wid  = threadIdx.x >> 6;
    const int lane = threadIdx.x & 63;
    const int eg   = lane >> 3;
    const int co   = lane & 7;

    const int  row = blockIdx.x * 32 + wid * 8 + eg;   // group eg owns this row
    const bool hr  = (row < N);

    const int   s0 = hr ? ptr[row] : 0;
    const int   s1 = hr ? ptr[row + 1] : 0;
    const float di = hr ? dis[row] : 0.f;
    const int   iters = (s1 - s0) >> 3;   // slabs are 8-padded

    float acc[8] = {};
    gather8_pad(B, csrw, s0, iters, co, acc);

    if (!hr) return;

    uint4 us = *(const uint4*)&B[(size_t)row * 64 + co * 8];
    float bs[8];
    bf8_unpack(us, bs);
    float bb[8];
    *(float4*)&bb[0] = *(const float4*)&b1[co * 8];
    *(float4*)&bb[4] = *(const float4*)&b1[co * 8 + 4];

    float h[8];
#pragma unroll
    for (int i = 0; i < 8; i++)
        h[i] = fmaxf((acc[i] + bs[i] * di) * di + bb[i], 0.f);

    *(float4*)&hs[(size_t)row * 64 + co * 8]     = make_float4(h[0], h[1], h[2], h[3]);
    *(float4*)&hs[(size_t)row * 64 + co * 8 + 4] = make_float4(h[4], h[5], h[6], h[7]);
}

// ---------------- layer 2: gather h2 + bias + log_softmax -> fp32 out --------------

__global__ __launch_bounds__(256) void agg_l2(const unsigned short* __restrict__ B,
                                              const int2* __restrict__ csrw,
                                              const int* __restrict__ ptr,
                                              const float* __restrict__ dis,
                                              const float* __restrict__ b2,
                                              float* __restrict__ out, int N) {
    const int wid  = threadIdx.x >> 6;
    const int lane = threadIdx.x & 63;
    const int eg   = lane >> 3;
    const int co   = lane & 7;

    const int  row = blockIdx.x * 32 + wid * 8 + eg;
    const bool hr  = (row < N);

    const int   s0 = hr ? ptr[row] : 0;
    const int   s1 = hr ? ptr[row + 1] : 0;
    const float di = hr ? dis[row] : 0.f;
    const int   iters = (s1 - s0) >> 3;

    float acc[8] = {};
    gather8_pad(B, csrw, s0, iters, co, acc);

    if (!hr) return;

    uint4 us = *(const uint4*)&B[(size_t)row * 64 + co * 8];
    float bs[8];
    bf8_unpack(us, bs);
    float bb[8];
    *(float4*)&bb[0] = *(const float4*)&b2[co * 8];
    *(float4*)&bb[4] = *(const float4*)&b2[co * 8 + 4];

    float v[8];
#pragma unroll
    for (int i = 0; i < 8; i++) v[i] = (acc[i] + bs[i] * di) * di + bb[i];

    float m = v[0];
#pragma unroll
    for (int i = 1; i < 8; i++) m = fmaxf(m, v[i]);
#pragma unroll
    for (int off = 1; off <= 4; off <<= 1) m = fmaxf(m, __shfl_xor(m, off));
    float s = 0.f;
#pragma unroll
    for (int i = 0; i < 8; i++) s += __expf(v[i] - m);
#pragma unroll
    for (int off = 1; off <= 4; off <<= 1) s += __shfl_xor(s, off);
    float lse = m + __logf(s);

    float4 oa = make_float4(v[0] - lse, v[1] - lse, v[2] - lse, v[3] - lse);
    float4 ob = make_float4(v[4] - lse, v[5] - lse, v[6] - lse, v[7] - lse);
    *(float4*)&out[(size_t)row * 64 + co * 8]     = oa;
    *(float4*)&out[(size_t)row * 64 + co * 8 + 4] = ob;
}

// ---------------- launch ----------------

extern "C" void kernel_launch(void* const* d_in, const int* in_sizes, int n_in,
                              void* d_out, int out_size, void* d_ws, size_t ws_size,
                              hipStream_t stream) {
    const float* x   = (const float*)d_in[0];
    const int*   ei  = (const int*)d_in[1];
    const float* W1  = (const float*)d_in[2];
    const float* b1  = (const float*)d_in[3];
    const float* W2  = (const float*)d_in[4];
    const float* b2  = (const float*)d_in[5];
    float*       out = (float*)d_out;

    const int  N   = in_sizes[0] / 128;
    const int  E   = in_sizes[1] / 2;
    const int* src = ei;
    const int* dst = ei + E;
    const int  NB  = (N + 1023) / 1024;

    int shift = 9;
    while (((N - 1) >> shift) >= 256) shift++;
    const int NBUCK = ((N - 1) >> shift) + 1;
    const int CAP   = ((E / NBUCK) * 3 / 2 + 255) & ~255;

    auto align256 = [](size_t v) { return (v + 255) & ~(size_t)255; };
    char*           p        = (char*)d_ws;
    float*          dis      = (float*)p;          p += align256((size_t)N * 4);
    int*            ptr      = (int*)p;            p += align256((size_t)(N + 1) * 4);
    int*            hist     = (int*)p;            p += align256((size_t)N * 4);
    int*            partials = (int*)p;            p += align256((size_t)NB * 4);
    int*            bcur     = (int*)p;            p += align256(256 * 4);
    int2*           csrw     = (int2*)p;           p += align256(((size_t)E + 8 * (size_t)N) * 8);
    int2*           bbuf     = (int2*)p;           p += align256((size_t)NBUCK * CAP * 8);
    unsigned short* xwb      = (unsigned short*)p; p += align256((size_t)N * 64 * 2);
    unsigned short* hwb      = (unsigned short*)p; p += align256((size_t)N * 64 * 2);

    // h (post-relu, f32) scratch lives in d_out: dead until agg_l2 overwrites it.
    float* hs = out;

    bcur_init<<<1, 256, 0, stream>>>(bcur, NBUCK, CAP);
    passA<<<(E + PASSA_EDGES - 1) / PASSA_EDGES, 256, 0, stream>>>(src, dst, bcur, bbuf, E, CAP, shift);
    hist_dis<<<NBUCK, 256, 0, stream>>>(bbuf, bcur, hist, dis, N, CAP, shift);
    scan_partial<<<NB, 256, 0, stream>>>(hist, partials, N);
    scan_offsets<<<1, 256, 0, stream>>>(partials, NB);
    scan_apply<<<NB, 256, 0, stream>>>(hist, partials, ptr, N);
    passB<<<NBUCK, 256, 0, stream>>>(bbuf, bcur, ptr, csrw, dis, N, CAP, shift);

    gemm64_bf16<128><<<(N + 63) / 64, 256, 0, stream>>>(x, W1, xwb, N);
    agg_l1<<<(N + 31) / 32, 256, 0, stream>>>(xwb, csrw, ptr, dis, b1, hs, N);
    // gemm2 de-fused: h2(bf16, reuses dead xwb) = h(f32, in d_out) @ W2
    gemm64_bf16<64><<<(N + 63) / 64, 256, 0, stream>>>(hs, W2, xwb, N);
    agg_l2<<<(N + 31) / 32, 256, 0, stream>>>(xwb, csrw, ptr, dis, b2, out, N);
}

// Round 5
// 266.898 us; speedup vs baseline: 1.0797x; 1.0797x over previous
//
#include <hip/hip_runtime.h>
#include <cstdint>
#include <cstddef>

#define PASSA_EDGES 8192
#define PASSB_CAP   12288   // LDS csr-image capacity (ints); padded max bucket ~10.5k for this input

typedef __attribute__((ext_vector_type(8))) short bf16x8;   // 8 bf16 = 4 VGPR (MFMA A/B frag)
typedef __attribute__((ext_vector_type(4))) float f32x4;    // MFMA C/D frag

// ---------------- bf16 helpers ----------------

__device__ __forceinline__ unsigned short f2bf(float f) {  // RNE
    unsigned int u = __float_as_uint(f);
    u += 0x7FFFu + ((u >> 16) & 1u);
    return (unsigned short)(u >> 16);
}
__device__ __forceinline__ float bf2f(unsigned short h) {
    return __uint_as_float((unsigned int)h << 16);
}

// fma 8 bf16 (packed in uint4) * w into acc[8]
__device__ __forceinline__ void bf8_fma(uint4 u, float w, float* acc) {
    acc[0] += __uint_as_float(u.x << 16) * w;
    acc[1] += __uint_as_float(u.x & 0xFFFF0000u) * w;
    acc[2] += __uint_as_float(u.y << 16) * w;
    acc[3] += __uint_as_float(u.y & 0xFFFF0000u) * w;
    acc[4] += __uint_as_float(u.z << 16) * w;
    acc[5] += __uint_as_float(u.z & 0xFFFF0000u) * w;
    acc[6] += __uint_as_float(u.w << 16) * w;
    acc[7] += __uint_as_float(u.w & 0xFFFF0000u) * w;
}
__device__ __forceinline__ void bf8_unpack(uint4 u, float* v) {
    v[0] = __uint_as_float(u.x << 16);
    v[1] = __uint_as_float(u.x & 0xFFFF0000u);
    v[2] = __uint_as_float(u.y << 16);
    v[3] = __uint_as_float(u.y & 0xFFFF0000u);
    v[4] = __uint_as_float(u.z << 16);
    v[5] = __uint_as_float(u.z & 0xFFFF0000u);
    v[6] = __uint_as_float(u.w << 16);
    v[7] = __uint_as_float(u.w & 0xFFFF0000u);
}

// ---------------- bucket cursor init ----------------

__global__ void bcur_init(int* __restrict__ bcur, int NBUCK, int CAP) {
    int b = threadIdx.x;
    if (b < NBUCK) bcur[b] = b * CAP;
}

// ---------------- pass A: bin (src,dst) by coarse dst bucket into slabs ----------------

__global__ __launch_bounds__(256) void passA(const int* __restrict__ src,
                                             const int* __restrict__ dst,
                                             int* __restrict__ bcur,
                                             int2* __restrict__ bbuf, int E,
                                             int CAP, int shift) {
    __shared__ int2 bins[PASSA_EDGES];
    __shared__ int  cnt[256], off[256], cur[256], gbase[256];
    const int t  = threadIdx.x;
    const int e0 = blockIdx.x * PASSA_EDGES;
    const int n  = min(PASSA_EDGES, E - e0);

    cnt[t] = 0;
    __syncthreads();
    for (int i = t; i < n; i += 256) atomicAdd(&cnt[dst[e0 + i] >> shift], 1);
    __syncthreads();

    int v = cnt[t];
    off[t] = v;
    __syncthreads();
    for (int o = 1; o < 256; o <<= 1) {
        int u = (t >= o) ? off[t - o] : 0;
        __syncthreads();
        off[t] += u;
        __syncthreads();
    }
    int excl = off[t] - v;
    off[t]   = excl;
    cur[t]   = excl;
    __syncthreads();

    for (int i = t; i < n; i += 256) {
        int d = dst[e0 + i];
        int s = src[e0 + i];
        int p = atomicAdd(&cur[d >> shift], 1);
        bins[p] = make_int2(s, d);
    }
    if (cnt[t] > 0) gbase[t] = atomicAdd(&bcur[t], cnt[t]);
    __syncthreads();

    const int w = t >> 6, lane = t & 63;
    for (int b = w; b < 256; b += 4) {
        int c = cnt[b];
        if (c == 0) continue;
        int lo  = off[b], go = gbase[b];
        int lim = (b + 1) * CAP;
        if (go + c > lim) c = max(0, lim - go);
        for (int i = lane; i < c; i += 64) bbuf[go + i] = bins[lo + i];
    }
}

// ---------------- per-bucket histogram + dis ----------------
// hist holds the 8-PADDED degree (slab quantum for the shuffle-free gather);
// dis uses the true degree.

__global__ __launch_bounds__(256) void hist_dis(const int2* __restrict__ bbuf,
                                                const int* __restrict__ bcur,
                                                int* __restrict__ hist,
                                                float* __restrict__ dis,
                                                int N, int CAP, int shift) {
    __shared__ int cnt[1024];
    const int b     = blockIdx.x;
    const int node0 = b << shift;
    const int nn    = min(1 << shift, N - node0);
    for (int j = threadIdx.x; j < nn; j += 256) cnt[j] = 0;
    __syncthreads();
    const int start = b * CAP, end = bcur[b];
    for (int e = start + threadIdx.x; e < end; e += 256)
        atomicAdd(&cnt[bbuf[e].y - node0], 1);
    __syncthreads();
    for (int j = threadIdx.x; j < nn; j += 256) {
        int c = cnt[j];
        hist[node0 + j] = (c + 7) & ~7;            // padded slab size
        dis[node0 + j]  = rsqrtf((float)(c + 1));  // +1 self loop (true degree)
    }
}

// ---------------- 3-phase exclusive scan hist[0..N) -> ptr[0..N] ----------------

__global__ __launch_bounds__(256) void scan_partial(const int* __restrict__ hist,
                                                    int* __restrict__ partials, int N) {
    __shared__ int red[256];
    const int t    = threadIdx.x;
    const int base = blockIdx.x * 1024 + t * 4;
    int s = 0;
    if (base + 3 < N) {
        int4 v = *(const int4*)&hist[base];
        s = v.x + v.y + v.z + v.w;
    } else {
        for (int i = 0; i < 4; i++)
            if (base + i < N) s += hist[base + i];
    }
    red[t] = s;
    __syncthreads();
    for (int off = 128; off; off >>= 1) {
        if (t < off) red[t] += red[t + off];
        __syncthreads();
    }
    if (t == 0) partials[blockIdx.x] = red[0];
}

__global__ __launch_bounds__(256) void scan_offsets(int* __restrict__ partials, int NB) {
    __shared__ int tmp[256];
    const int t = threadIdx.x;
    int v = (t < NB) ? partials[t] : 0;
    tmp[t] = v;
    __syncthreads();
    for (int off = 1; off < 256; off <<= 1) {
        int u = (t >= off) ? tmp[t - off] : 0;
        __syncthreads();
        tmp[t] += u;
        __syncthreads();
    }
    if (t < NB) partials[t] = tmp[t] - v;
}

__global__ __launch_bounds__(256) void scan_apply(const int* __restrict__ hist,
                                                  const int* __restrict__ partials,
                                                  int* __restrict__ ptr, int N) {
    __shared__ int tsum[256];
    const int t    = threadIdx.x;
    const int base = blockIdx.x * 1024 + t * 4;
    int v[4];
    int s = 0;
    for (int i = 0; i < 4; i++) {
        v[i] = (base + i < N) ? hist[base + i] : 0;
        s += v[i];
    }
    tsum[t] = s;
    __syncthreads();
    for (int off = 1; off < 256; off <<= 1) {
        int u = (t >= off) ? tsum[t - off] : 0;
        __syncthreads();
        tsum[t] += u;
        __syncthreads();
    }
    int run = partials[blockIdx.x] + tsum[t] - s;
    for (int i = 0; i < 4; i++) {
        if (base + i < N) {
            ptr[base + i] = run;
            run += v[i];
        }
    }
    if (base <= N - 1 && N - 1 < base + 4) ptr[N] = run;  // total = padded E
}

// ---------------- pass B: per-bucket LDS scatter -> padded (src,w) csr write -------
// csrw[e] = {src, bitcast(dis[src])}; pad slots (up to 7 per row) = {0, 0.0f}:
// they load row 0 (L1-hot) and fma by 0 in the gather -- branch-free slop.

__global__ __launch_bounds__(256) void passB(const int2* __restrict__ bbuf,
                                             const int* __restrict__ bcur,
                                             const int* __restrict__ ptr,
                                             int2* __restrict__ csrw,
                                             const float* __restrict__ dis,
                                             int N, int CAP, int shift) {
    __shared__ int lcnt[1024];
    __shared__ int lcsr[PASSB_CAP];
    const int b     = blockIdx.x;
    const int node0 = b << shift;
    const int nn    = min(1 << shift, N - node0);
    const int cbase = ptr[node0];
    const int csize = ptr[node0 + nn] - cbase;   // padded size

    for (int j = threadIdx.x; j < nn; j += 256) lcnt[j] = ptr[node0 + j] - cbase;
    __syncthreads();

    const int start = b * CAP, end = bcur[b];
    if (csize <= PASSB_CAP) {
        for (int i = threadIdx.x; i < csize; i += 256) lcsr[i] = -1;  // pad marker
        __syncthreads();
        for (int e = start + threadIdx.x; e < end; e += 256) {
            int2 pr = bbuf[e];
            int  p  = atomicAdd(&lcnt[pr.y - node0], 1);
            lcsr[p] = pr.x;
        }
        __syncthreads();
        for (int i = threadIdx.x; i < csize; i += 256) {
            int s = lcsr[i];
            csrw[cbase + i] = (s < 0) ? make_int2(0, 0)
                                      : make_int2(s, __float_as_int(dis[s]));
        }
    } else {  // fallback: default-fill then direct global scatter
        for (int i = threadIdx.x; i < csize; i += 256) csrw[cbase + i] = make_int2(0, 0);
        __syncthreads();
        for (int e = start + threadIdx.x; e < end; e += 256) {
            int2 pr = bbuf[e];
            int  p  = atomicAdd(&lcnt[pr.y - node0], 1);
            csrw[cbase + p] = make_int2(pr.x, __float_as_int(dis[pr.x]));
        }
    }
}

// ---------------- W fragment prep: fp32 W -> fragment-ordered bf16 hi/lo ----------
// B-frag layout for mfma_f32_16x16x32_bf16: lane&15 = out-col n, lane>>4 = k-octet,
// 8 contiguous k per lane. Stored so lane l of frag-block (kstep*4+nt) reads its
// 16 B contiguously at [(kstep*4+nt)*512 + l*8]. hi = RNE(w); lo = RNE(w - hi):
// Xhi*Whi + Xlo*Whi + Xhi*Wlo reproduces fp32 to ~2^-17 (lo*lo dropped).

__global__ __launch_bounds__(256) void prep_wfrag(const float* __restrict__ W1,
                                                  const float* __restrict__ W2,
                                                  unsigned short* __restrict__ whi1,
                                                  unsigned short* __restrict__ wlo1,
                                                  unsigned short* __restrict__ whi2,
                                                  unsigned short* __restrict__ wlo2) {
    for (int e = threadIdx.x; e < 128 * 64; e += 256) {
        const int blk = e >> 9, l = (e >> 3) & 63, j = e & 7;
        const int k = (blk >> 2) * 32 + (l >> 4) * 8 + j;
        const int n = (blk & 3) * 16 + (l & 15);
        const float v = W1[k * 64 + n];
        const unsigned short h = f2bf(v);
        whi1[e] = h;
        wlo1[e] = f2bf(v - bf2f(h));
    }
    for (int e = threadIdx.x; e < 64 * 64; e += 256) {
        const int blk = e >> 9, l = (e >> 3) & 63, j = e & 7;
        const int k = (blk >> 2) * 32 + (l >> 4) * 8 + j;
        const int n = (blk & 3) * 16 + (l & 15);
        const float v = W2[k * 64 + n];
        const unsigned short h = f2bf(v);
        whi2[e] = h;
        wlo2[e] = f2bf(v - bf2f(h));
    }
}

// ---------------- MFMA GEMM: Yb[N x 64](bf16) = X[N x K](f32) @ W[K x 64] ----------
// R5: 64-row tile, 4 waves (wave w owns rows w*16..w*16+15). X staged fp32 into
// padded LDS (LDX=K+4 makes the A-frag read pattern bank-balanced: 16B-slot =
// (m + 2*kg) mod 8). A-frag: lane&15 = row m, lane>>4 = k-octet (8 contiguous k),
// split to bf16 hi/lo in-register. B-frags: coalesced 16 B/lane global loads from
// the prep arrays (48 KB, L2-hot). 3 MFMA per (kstep,ntile) = split-fp32 accuracy.
// C/D: col = lane&15, row = (lane>>4)*4 + reg [m89-verified mapping].

template <int K>
__global__ __launch_bounds__(256) void gemm_mfma(const float* __restrict__ X,
                                                 const unsigned short* __restrict__ whi,
                                                 const unsigned short* __restrict__ wlo,
                                                 unsigned short* __restrict__ Yb, int N) {
    constexpr int LDX = K + 4;
    __shared__ float xs[64 * LDX];
    const int tid  = threadIdx.x;
    const int row0 = blockIdx.x * 64;

#pragma unroll
    for (int i = 0; i < (64 * K) / 1024; ++i) {
        const int fidx = i * 1024 + tid * 4;
        const int r = fidx / K, c = fidx % K;
        const float4 v = *(const float4*)(X + (size_t)min(row0 + r, N - 1) * K + c);
        *(float4*)&xs[r * LDX + c] = v;
    }
    __syncthreads();

    const int w = tid >> 6, l = tid & 63;
    const int m = l & 15, kg = l >> 4;

    f32x4 acc[4] = {};
    const float* xrow = &xs[(w * 16 + m) * LDX];

#pragma unroll
    for (int s = 0; s < K / 32; ++s) {
        const float4 a0 = *(const float4*)(xrow + s * 32 + kg * 8);
        const float4 a1 = *(const float4*)(xrow + s * 32 + kg * 8 + 4);
        const float av[8] = {a0.x, a0.y, a0.z, a0.w, a1.x, a1.y, a1.z, a1.w};
        bf16x8 ahi, alo;
#pragma unroll
        for (int j = 0; j < 8; ++j) {
            const unsigned short h = f2bf(av[j]);
            ahi[j] = (short)h;
            alo[j] = (short)f2bf(av[j] - bf2f(h));
        }
#pragma unroll
        for (int nt = 0; nt < 4; ++nt) {
            const bf16x8 bh = *(const bf16x8*)&whi[(s * 4 + nt) * 512 + l * 8];
            const bf16x8 bl = *(const bf16x8*)&wlo[(s * 4 + nt) * 512 + l * 8];
            acc[nt] = __builtin_amdgcn_mfma_f32_16x16x32_bf16(ahi, bh, acc[nt], 0, 0, 0);
            acc[nt] = __builtin_amdgcn_mfma_f32_16x16x32_bf16(alo, bh, acc[nt], 0, 0, 0);
            acc[nt] = __builtin_amdgcn_mfma_f32_16x16x32_bf16(ahi, bl, acc[nt], 0, 0, 0);
        }
    }

#pragma unroll
    for (int nt = 0; nt < 4; ++nt)
#pragma unroll
        for (int r = 0; r < 4; ++r) {
            const int row = row0 + w * 16 + kg * 4 + r;
            if (row < N) Yb[(size_t)row * 64 + nt * 16 + m] = f2bf(acc[nt][r]);
        }
}

// ---------------- shuffle-free oct-row gather: 8 rows/wave, group-per-row ----------
// Row slabs are 8-padded (s0 % 8 == 0), so each lane loads its group's whole
// (src,w) chunk directly as 4 x int4 (64B, all 8 group lanes hit the same L1
// lines -> broadcast). No ds_bpermute, no bounds predication in the loop.
// Next chunk is prefetched one iteration ahead; 8 independent B-row loads are
// in flight per lane per iteration. Groups exit independently (divergence safe).

__device__ __forceinline__ void gather8_pad(const unsigned short* __restrict__ B,
                                            const int2* __restrict__ csrw,
                                            int s0, int iters, int co, float* acc) {
    const int4* cs = (const int4*)(csrw + s0);  // 64B-aligned (s0 % 8 == 0)
    int4 c0 = make_int4(0, 0, 0, 0), c1 = c0, c2 = c0, c3 = c0;
    if (iters > 0) { c0 = cs[0]; c1 = cs[1]; c2 = cs[2]; c3 = cs[3]; }
    for (int it = 0; it < iters; ++it) {
        const int nb = min(it + 1, iters - 1) * 4;   // prefetch next chunk (clamped)
        int4 n0 = cs[nb], n1 = cs[nb + 1], n2 = cs[nb + 2], n3 = cs[nb + 3];
        uint4 u0 = *(const uint4*)&B[(size_t)c0.x * 64 + co * 8];
        uint4 u1 = *(const uint4*)&B[(size_t)c0.z * 64 + co * 8];
        uint4 u2 = *(const uint4*)&B[(size_t)c1.x * 64 + co * 8];
        uint4 u3 = *(const uint4*)&B[(size_t)c1.z * 64 + co * 8];
        uint4 u4 = *(const uint4*)&B[(size_t)c2.x * 64 + co * 8];
        uint4 u5 = *(const uint4*)&B[(size_t)c2.z * 64 + co * 8];
        uint4 u6 = *(const uint4*)&B[(size_t)c3.x * 64 + co * 8];
        uint4 u7 = *(const uint4*)&B[(size_t)c3.z * 64 + co * 8];
        bf8_fma(u0, __int_as_float(c0.y), acc);
        bf8_fma(u1, __int_as_float(c0.w), acc);
        bf8_fma(u2, __int_as_float(c1.y), acc);
        bf8_fma(u3, __int_as_float(c1.w), acc);
        bf8_fma(u4, __int_as_float(c2.y), acc);
        bf8_fma(u5, __int_as_float(c2.w), acc);
        bf8_fma(u6, __int_as_float(c3.y), acc);
        bf8_fma(u7, __int_as_float(c3.w), acc);
        c0 = n0; c1 = n1; c2 = n2; c3 = n3;
    }
}

// ---------------- layer 1: pure gather + relu -> f32 h (scratch = d_out) -----------

__global__ __launch_bounds__(256) void agg_l1(const unsigned short* __restrict__ B,
                                              const int2* __restrict__ csrw,
                                              const int* __restrict__ ptr,
                                              const float* __restrict__ dis,
                                              const float* __restrict__ b1,
                                              float* __restrict__ hs, int N) {
    const int wid  = threadIdx.x >> 6;
    const int lane = threadIdx.x & 63;
    const int eg   = lane >> 3;
    const int co   = lane & 7;

    const int  row = blockIdx.x * 32 + wid * 8 + eg;   // group eg owns this row
    const bool hr  = (row < N);

    const int   s0 = hr ? ptr[row] : 0;
    const int   s1 = hr ? ptr[row + 1] : 0;
    const float di = hr ? dis[row] : 0.f;
    const int   iters = (s1 - s0) >> 3;   // slabs are 8-padded

    float acc[8] = {};
    gather8_pad(B, csrw, s0, iters, co, acc);

    if (!hr) return;

    uint4 us = *(const uint4*)&B[(size_t)row * 64 + co * 8];
    float bs[8];
    bf8_unpack(us, bs);
    float bb[8];
    *(float4*)&bb[0] = *(const float4*)&b1[co * 8];
    *(float4*)&bb[4] = *(const float4*)&b1[co * 8 + 4];

    float h[8];
#pragma unroll
    for (int i = 0; i < 8; i++)
        h[i] = fmaxf((acc[i] + bs[i] * di) * di + bb[i], 0.f);

    *(float4*)&hs[(size_t)row * 64 + co * 8]     = make_float4(h[0], h[1], h[2], h[3]);
    *(float4*)&hs[(size_t)row * 64 + co * 8 + 4] = make_float4(h[4], h[5], h[6], h[7]);
}

// ---------------- layer 2: gather h2 + bias + log_softmax -> fp32 out --------------

__global__ __launch_bounds__(256) void agg_l2(const unsigned short* __restrict__ B,
                                              const int2* __restrict__ csrw,
                                              const int* __restrict__ ptr,
                                              const float* __restrict__ dis,
                                              const float* __restrict__ b2,
                                              float* __restrict__ out, int N) {
    const int wid  = threadIdx.x >> 6;
    const int lane = threadIdx.x & 63;
    const int eg   = lane >> 3;
    const int co   = lane & 7;

    const int  row = blockIdx.x * 32 + wid * 8 + eg;
    const bool hr  = (row < N);

    const int   s0 = hr ? ptr[row] : 0;
    const int   s1 = hr ? ptr[row + 1] : 0;
    const float di = hr ? dis[row] : 0.f;
    const int   iters = (s1 - s0) >> 3;

    float acc[8] = {};
    gather8_pad(B, csrw, s0, iters, co, acc);

    if (!hr) return;

    uint4 us = *(const uint4*)&B[(size_t)row * 64 + co * 8];
    float bs[8];
    bf8_unpack(us, bs);
    float bb[8];
    *(float4*)&bb[0] = *(const float4*)&b2[co * 8];
    *(float4*)&bb[4] = *(const float4*)&b2[co * 8 + 4];

    float v[8];
#pragma unroll
    for (int i = 0; i < 8; i++) v[i] = (acc[i] + bs[i] * di) * di + bb[i];

    float m = v[0];
#pragma unroll
    for (int i = 1; i < 8; i++) m = fmaxf(m, v[i]);
#pragma unroll
    for (int off = 1; off <= 4; off <<= 1) m = fmaxf(m, __shfl_xor(m, off));
    float s = 0.f;
#pragma unroll
    for (int i = 0; i < 8; i++) s += __expf(v[i] - m);
#pragma unroll
    for (int off = 1; off <= 4; off <<= 1) s += __shfl_xor(s, off);
    float lse = m + __logf(s);

    float4 oa = make_float4(v[0] - lse, v[1] - lse, v[2] - lse, v[3] - lse);
    float4 ob = make_float4(v[4] - lse, v[5] - lse, v[6] - lse, v[7] - lse);
    *(float4*)&out[(size_t)row * 64 + co * 8]     = oa;
    *(float4*)&out[(size_t)row * 64 + co * 8 + 4] = ob;
}

// ---------------- launch ----------------

extern "C" void kernel_launch(void* const* d_in, const int* in_sizes, int n_in,
                              void* d_out, int out_size, void* d_ws, size_t ws_size,
                              hipStream_t stream) {
    const float* x   = (const float*)d_in[0];
    const int*   ei  = (const int*)d_in[1];
    const float* W1  = (const float*)d_in[2];
    const float* b1  = (const float*)d_in[3];
    const float* W2  = (const float*)d_in[4];
    const float* b2  = (const float*)d_in[5];
    float*       out = (float*)d_out;

    const int  N   = in_sizes[0] / 128;
    const int  E   = in_sizes[1] / 2;
    const int* src = ei;
    const int* dst = ei + E;
    const int  NB  = (N + 1023) / 1024;

    int shift = 9;
    while (((N - 1) >> shift) >= 256) shift++;
    const int NBUCK = ((N - 1) >> shift) + 1;
    const int CAP   = ((E / NBUCK) * 3 / 2 + 255) & ~255;

    auto align256 = [](size_t v) { return (v + 255) & ~(size_t)255; };
    char*           p        = (char*)d_ws;
    float*          dis      = (float*)p;          p += align256((size_t)N * 4);
    int*            ptr      = (int*)p;            p += align256((size_t)(N + 1) * 4);
    int*            hist     = (int*)p;            p += align256((size_t)N * 4);
    int*            partials = (int*)p;            p += align256((size_t)NB * 4);
    int*            bcur     = (int*)p;            p += align256(256 * 4);
    int2*           csrw     = (int2*)p;           p += align256(((size_t)E + 8 * (size_t)N) * 8);
    int2*           bbuf     = (int2*)p;           p += align256((size_t)NBUCK * CAP * 8);
    unsigned short* xwb      = (unsigned short*)p; p += align256((size_t)N * 64 * 2);
    unsigned short* whi1     = (unsigned short*)p; p += align256(128 * 64 * 2);
    unsigned short* wlo1     = (unsigned short*)p; p += align256(128 * 64 * 2);
    unsigned short* whi2     = (unsigned short*)p; p += align256(64 * 64 * 2);
    unsigned short* wlo2     = (unsigned short*)p; p += align256(64 * 64 * 2);

    // h (post-relu, f32) scratch lives in d_out: dead until agg_l2 overwrites it.
    float* hs = out;

    bcur_init<<<1, 256, 0, stream>>>(bcur, NBUCK, CAP);
    prep_wfrag<<<1, 256, 0, stream>>>(W1, W2, whi1, wlo1, whi2, wlo2);
    passA<<<(E + PASSA_EDGES - 1) / PASSA_EDGES, 256, 0, stream>>>(src, dst, bcur, bbuf, E, CAP, shift);
    hist_dis<<<NBUCK, 256, 0, stream>>>(bbuf, bcur, hist, dis, N, CAP, shift);
    scan_partial<<<NB, 256, 0, stream>>>(hist, partials, N);
    scan_offsets<<<1, 256, 0, stream>>>(partials, NB);
    scan_apply<<<NB, 256, 0, stream>>>(hist, partials, ptr, N);
    passB<<<NBUCK, 256, 0, stream>>>(bbuf, bcur, ptr, csrw, dis, N, CAP, shift);

    gemm_mfma<128><<<(N + 63) / 64, 256, 0, stream>>>(x, whi1, wlo1, xwb, N);
    agg_l1<<<(N + 31) / 32, 256, 0, stream>>>(xwb, csrw, ptr, dis, b1, hs, N);
    // gemm2: h2(bf16, reuses dead xwb) = h(f32, in d_out) @ W2
    gemm_mfma<64><<<(N + 63) / 64, 256, 0, stream>>>(hs, whi2, wlo2, xwb, N);
    agg_l2<<<(N + 31) / 32, 256, 0, stream>>>(xwb, csrw, ptr, dis, b2, out, N);
}